// Round 8
// baseline (180.074 us; speedup 1.0000x reference)
//
#include <hip/hip_runtime.h>
#include <math.h>

#define NHEADS 16
#define HD 64
#define SEQ 2048
#define BATCH 2
#define DM 1024
#define MTOT (BATCH*SEQ)   // 4096

typedef __bf16 bf16x8 __attribute__((ext_vector_type(8)));
typedef __bf16 bf16x4 __attribute__((ext_vector_type(4)));
typedef __bf16 bf16x2 __attribute__((ext_vector_type(2)));
typedef float  f32x4  __attribute__((ext_vector_type(4)));
typedef float  f32x16 __attribute__((ext_vector_type(16)));
typedef unsigned u32x4 __attribute__((ext_vector_type(4)));

#define LOG2E 1.4426950408889634f

// async global->LDS, 16B per lane; LDS side is wave-uniform base + lane*16
#define GLD16(gp, lp) __builtin_amdgcn_global_load_lds( \
    (const __attribute__((address_space(1))) void*)(gp), \
    (__attribute__((address_space(3))) void*)(lp), 16, 0, 0)

// ---------------- cast: x -> bf16, [Wq;Wk;Wv] -> Wqkv bf16, Wo -> bf16 ----
__global__ __launch_bounds__(256)
void cast_all(const float* __restrict__ x, const float* __restrict__ Wq,
              const float* __restrict__ Wk, const float* __restrict__ Wv,
              const float* __restrict__ Wo,
              __bf16* __restrict__ xb, __bf16* __restrict__ Wqkvb,
              __bf16* __restrict__ Wob)
{
    const size_t NX = (size_t)MTOT * DM;   // 4M
    const size_t NW_ = (size_t)DM * DM;    // 1M
    const size_t i = ((size_t)blockIdx.x * 256 + threadIdx.x) * 8;
    const float* src; __bf16* dst; size_t off;
    if (i < NX)               { src = x;  dst = xb;            off = i; }
    else if (i < NX + NW_)    { src = Wq; dst = Wqkvb;         off = i - NX; }
    else if (i < NX + 2*NW_)  { src = Wk; dst = Wqkvb + NW_;   off = i - NX - NW_; }
    else if (i < NX + 3*NW_)  { src = Wv; dst = Wqkvb + 2*NW_; off = i - NX - 2*NW_; }
    else                      { src = Wo; dst = Wob;           off = i - NX - 3*NW_; }
    const float4 f0 = *(const float4*)&src[off];
    const float4 f1 = *(const float4*)&src[off + 4];
    bf16x8 o;
    o[0] = (__bf16)f0.x; o[1] = (__bf16)f0.y; o[2] = (__bf16)f0.z; o[3] = (__bf16)f0.w;
    o[4] = (__bf16)f1.x; o[5] = (__bf16)f1.y; o[6] = (__bf16)f1.z; o[7] = (__bf16)f1.w;
    *(bf16x8*)&dst[off] = o;
}

// ---------------- MFMA GEMM: C[m,n] = sum_k A[m,k]*W[n,k], K=1024 ---------
// BM x BN tile, BK=64, 4 waves in 2x2 (wave-tile BM/2 x BN/2).
// LDS granules (16B) XOR-swizzled: global granule g of row r at slot g^(r&7)
// -> fragment ds_read_b128 spreads over all 8 bank groups (2-way = free).
// (256,3): ~168-reg cap fits 128x128 acc[4][4]; 3 blocks/CU.
// MODE 0: QKV epilogue with FUSED RoPE (Q scaled by 0.125*log2e, base-2
// softmax domain); Q/K -> [b,h,s,d] bf16, V -> [b,h,d,s] bf16.
// MODE 1: plain fp32 C.
template<int BM, int BN, int MODE>
__global__ __launch_bounds__(256, 3)
void gemm_mfma(const __bf16* __restrict__ A, const __bf16* __restrict__ W,
               float* __restrict__ Cf,
               __bf16* __restrict__ Qb, __bf16* __restrict__ Kb,
               __bf16* __restrict__ Vtb)
{
    constexpr int IT = BM / 32;        // i-tiles per wave
    constexpr int JT = BN / 32;        // j-tiles per wave
    __shared__ __bf16 As[BM * 64];
    __shared__ __bf16 Bs[BN * 64];

    const int tid  = threadIdx.x;
    const int lane = tid & 63;
    const int wave = tid >> 6;
    const int ll   = lane & 15;
    const int quad = lane >> 4;
    const int wm   = (wave & 1) * (BM / 2);
    const int wn   = (wave >> 1) * (BN / 2);
    const int bm   = blockIdx.x * BM;
    const int bn   = blockIdx.y * BN;

    const __bf16* Ab = A + (size_t)bm * DM;
    const __bf16* Wb = W + (size_t)bn * DM;

    f32x4 acc[IT][JT];
#pragma unroll
    for (int i = 0; i < IT; i++)
#pragma unroll
        for (int j = 0; j < JT; j++) acc[i][j] = (f32x4){0.f, 0.f, 0.f, 0.f};

    for (int k0 = 0; k0 < DM; k0 += 64) {
#pragma unroll
        for (int j = 0; j < BM / 32; j++) {
            const int t = tid + 256 * j;
            const int r = t >> 3, g = t & 7;
            GLD16(Ab + (size_t)r * DM + k0 + ((g ^ (r & 7)) * 8), &As[t * 8]);
        }
#pragma unroll
        for (int j = 0; j < BN / 32; j++) {
            const int t = tid + 256 * j;
            const int r = t >> 3, g = t & 7;
            GLD16(Wb + (size_t)r * DM + k0 + ((g ^ (r & 7)) * 8), &Bs[t * 8]);
        }
        __syncthreads();   // drains vmcnt -> LDS tiles valid

#pragma unroll
        for (int kh = 0; kh < 2; kh++) {
            bf16x8 af[IT], bfr[JT];
#pragma unroll
            for (int i = 0; i < IT; i++) {
                const int r = wm + i*16 + ll;
                const int g = kh*4 + quad;
                af[i] = *(const bf16x8*)&As[(r*8 + (g ^ (r & 7))) * 8];
            }
#pragma unroll
            for (int j = 0; j < JT; j++) {
                const int r = wn + j*16 + ll;
                const int g = kh*4 + quad;
                bfr[j] = *(const bf16x8*)&Bs[(r*8 + (g ^ (r & 7))) * 8];
            }
#pragma unroll
            for (int i = 0; i < IT; i++)
#pragma unroll
                for (int j = 0; j < JT; j++)
                    acc[i][j] = __builtin_amdgcn_mfma_f32_16x16x32_bf16(
                        af[i], bfr[j], acc[i][j], 0, 0, 0);
        }
        __syncthreads();
    }

    if (MODE == 1) {
#pragma unroll
        for (int i = 0; i < IT; i++) {
#pragma unroll
            for (int j = 0; j < JT; j++) {
                const int gc = bn + wn + j*16 + ll;
#pragma unroll
                for (int r = 0; r < 4; r++) {
                    const int gr = bm + wm + i*16 + quad*4 + r;
                    Cf[(size_t)gr * DM + gc] = acc[i][j][r];
                }
            }
        }
    } else {
        const int which = bn >> 10;    // 0=Q 1=K 2=V (BN-aligned within 1024)
        const int nb = bn & 1023;
#pragma unroll
        for (int i = 0; i < IT; i++) {
            const int m0 = bm + wm + i*16 + quad*4;
            const int b  = m0 >> 11;
            const int s0 = m0 & (SEQ - 1);
#pragma unroll
            for (int j = 0; j < JT; j++) {
                const int n_g = nb + wn + j*16 + ll;
                const int h = n_g >> 6, d = n_g & (HD - 1);
                if (which == 2) {
                    bf16x4 pk;
#pragma unroll
                    for (int r = 0; r < 4; r++) pk[r] = (__bf16)acc[i][j][r];
                    *(bf16x4*)&Vtb[((size_t)((b*NHEADS + h)*HD + d)) * SEQ + s0] = pk;
                } else {
                    // fused RoPE: pair (d even, d odd) sits in lanes (ll, ll^1)
                    __bf16* P = (which == 0) ? Qb : Kb;
                    const float sc = (which == 0) ? 0.125f * LOG2E : 1.0f;
                    const float inv =
                        exp2f(-(float)(d & ~1) * (13.287712379549449f / 64.0f));
                    const bool odd = (d & 1);
#pragma unroll
                    for (int r = 0; r < 4; r++) {
                        const float own = acc[i][j][r];
                        const float oth = __shfl_xor(own, 1);
                        float sn, cs;
                        __sincosf((float)(s0 + r) * inv, &sn, &cs);
                        const float xe = odd ? oth : own;
                        const float xo = odd ? own : oth;
                        const float o = odd ? (xe * sn + xo * cs)
                                            : (xe * cs - xo * sn);
                        P[((size_t)(b*NHEADS + h) * SEQ + s0 + r) * HD + d] =
                            (__bf16)(o * sc);
                    }
                }
            }
        }
    }
}

// pack 2 f32 -> 1 dword of 2 bf16 (elem0 = low bits)
static __device__ __forceinline__ unsigned pk2(float a, float b) {
    bf16x2 t; t[0] = (__bf16)a; t[1] = (__bf16)b;
    return __builtin_bit_cast(unsigned, t);
}

// ---------------- MFMA flash attention: 32x32, zero cross-lane P ----------
// R7: R5/R6's permlane exchange ELIMINATED. Swapped QK (s = mfma(K,Q)):
// lane l reg r holds P[q=l&31][k_local=(r&3)+8(r>>2)+4hi] (verified C/D map,
// same crow() as the guide's attn notes). PV A-fragment keeps each lane's
// OWN packed p's: kk slot order per 16-k chunk = {0,1,2,3,8,9,10,11}+4hi.
// Contraction is order-agnostic -> V (stored [d][s]) is loaded in the SAME
// permuted row order: two bf16x4 runs at s = 16c+4hi and 16c+8+4hi. No
// shuffles, no selects, no LDS in the main loop. lsum: both hi halves write
// separate lbuf slots; epilogue sums 8 partials. K-split 4 waves, balanced
// (32bh,16,2) grid as in R0.
// __launch_bounds__(256,2): cap 256 regs. NEVER cap at 128 (R9 spill note).
__global__ __launch_bounds__(256, 2)
void attn_mfma(const __bf16* __restrict__ Qb, const __bf16* __restrict__ Kb,
               const __bf16* __restrict__ Vtb, __bf16* __restrict__ AOb)
{
    __shared__ float comb[4][32][33];   // 16.9 KB
    __shared__ float lbuf[4][2][64];    // 2 KB

    const int tid  = threadIdx.x;
    const int wave = tid >> 6;
    const int lane = tid & 63;
    const int col  = lane & 31;         // q-col (QK) / d-col (PV)
    const int hi   = lane >> 5;
    const int bh   = blockIdx.x;
    const int b    = bh >> 4, h = bh & 15;
    const int qb   = blockIdx.z ? (SEQ/64 - 1) - (int)blockIdx.y : (int)blockIdx.y;
    const int q0   = qb * 64;

    const __bf16* Qp = Qb + (size_t)bh * SEQ * HD;
    const __bf16* Kp = Kb + (size_t)bh * SEQ * HD;
    const __bf16* Vp = Vtb + (size_t)bh * HD * SEQ;

    // Q fragments (B-operand): qf[i][c] = Q[q0+32i+col][16c+8hi .. +7]
    bf16x8 qf[2][4];
#pragma unroll
    for (int i = 0; i < 2; i++)
#pragma unroll
        for (int c = 0; c < 4; c++)
            qf[i][c] = *(const bf16x8*)&Qp[(size_t)(q0 + 32*i + col) * HD
                                           + 16*c + 8*hi];

    f32x16 acc[2][2];
#pragma unroll
    for (int i = 0; i < 2; i++)
#pragma unroll
        for (int dt = 0; dt < 2; dt++) acc[i][dt] = (f32x16){};
    float lsum[2] = {0.f, 0.f};

    const int cr = col - 4*hi;          // causal threshold helper

    for (int t = wave; t <= qb; t += 4) {
        const int k0 = t * 64;
        const bool diag = (t == qb);    // wave-uniform

        bf16x8 kf[2][4];
#pragma unroll
        for (int kt = 0; kt < 2; kt++)
#pragma unroll
            for (int c = 0; c < 4; c++)
                kf[kt][c] = *(const bf16x8*)&Kp[(size_t)(k0 + 32*kt + col) * HD
                                                + 16*c + 8*hi];
        // V in PERMUTED row order matching the A-side kk slots:
        // chunk c slot j<4 -> k = 16c+4hi+j ; slot j>=4 -> k = 16c+8+4hi+(j-4)
        bf16x4 vf[2][4][2];
#pragma unroll
        for (int dt = 0; dt < 2; dt++)
#pragma unroll
            for (int c = 0; c < 4; c++) {
                const __bf16* vrow = &Vp[(size_t)(32*dt + col) * SEQ + k0 + 16*c];
                vf[dt][c][0] = *(const bf16x4*)(vrow + 4*hi);
                vf[dt][c][1] = *(const bf16x4*)(vrow + 8 + 4*hi);
            }

#pragma unroll
        for (int i = 0; i < 2; i++) {
#pragma unroll
            for (int kt = 0; kt < 2; kt++) {
                if (kt > i && diag) continue;          // fully-masked sub-tile
                f32x16 s = (f32x16){};
#pragma unroll
                for (int c = 0; c < 4; c++)
                    s = __builtin_amdgcn_mfma_f32_32x32x16_bf16(
                        kf[kt][c], qf[i][c], s, 0, 0, 0);
                const bool tri = diag && (kt == i);
                float p[16];
#pragma unroll
                for (int r = 0; r < 16; r++) {
                    float sv = s[r];
                    if (tri && ((r & 3) + 8*(r >> 2) > cr)) sv = -INFINITY;
                    p[r] = __builtin_amdgcn_exp2f(sv);
                }
                float ls = ((p[0]+p[1])+(p[2]+p[3])) + ((p[4]+p[5])+(p[6]+p[7]))
                         + ((p[8]+p[9])+(p[10]+p[11])) + ((p[12]+p[13])+(p[14]+p[15]));
                lsum[i] += ls;
                // natural per-lane pack: a0 slots = k {0,1,2,3,8,9,10,11}+4hi,
                // a1 slots = k {16..19,24..27}+4hi (V loaded to match)
                const u32x4 w0 = {pk2(p[0],  p[1]),  pk2(p[2],  p[3]),
                                  pk2(p[4],  p[5]),  pk2(p[6],  p[7])};
                const u32x4 w1 = {pk2(p[8],  p[9]),  pk2(p[10], p[11]),
                                  pk2(p[12], p[13]), pk2(p[14], p[15])};
                const bf16x8 a0 = __builtin_bit_cast(bf16x8, w0);
                const bf16x8 a1 = __builtin_bit_cast(bf16x8, w1);
#pragma unroll
                for (int dt = 0; dt < 2; dt++) {
                    bf16x8 v0, v1;
#pragma unroll
                    for (int e = 0; e < 4; e++) {
                        v0[e]   = vf[dt][2*kt][0][e];
                        v0[4+e] = vf[dt][2*kt][1][e];
                        v1[e]   = vf[dt][2*kt+1][0][e];
                        v1[4+e] = vf[dt][2*kt+1][1][e];
                    }
                    acc[i][dt] = __builtin_amdgcn_mfma_f32_32x32x16_bf16(
                        a0, v0, acc[i][dt], 0, 0, 0);
                    acc[i][dt] = __builtin_amdgcn_mfma_f32_32x32x16_bf16(
                        a1, v1, acc[i][dt], 0, 0, 0);
                }
            }
        }
    }

    // ---- row-sum partials: both hi halves to separate lbuf slots ----
#pragma unroll
    for (int i = 0; i < 2; i++)
        lbuf[wave][hi][32*i + col] = lsum[i];
    __syncthreads();

    // ---- cross-wave combine, 4 rounds of (i,dt): 32q x 32d each ----
    const int qq  = tid >> 3;           // 0..31
    const int dd0 = (tid & 7) * 4;      // 0,4,...,28
#pragma unroll
    for (int i = 0; i < 2; i++) {
        float lt = 0.f;
#pragma unroll
        for (int w = 0; w < 4; w++)
            lt += lbuf[w][0][32*i + qq] + lbuf[w][1][32*i + qq];
        const float rl = 1.0f / lt;
#pragma unroll
        for (int dt = 0; dt < 2; dt++) {
#pragma unroll
            for (int r = 0; r < 16; r++)
                comb[wave][(r & 3) + 8*(r >> 2) + 4*hi][col] = acc[i][dt][r];
            __syncthreads();
            bf16x4 ov;
#pragma unroll
            for (int cc = 0; cc < 4; cc++) {
                const float o = comb[0][qq][dd0+cc] + comb[1][qq][dd0+cc]
                              + comb[2][qq][dd0+cc] + comb[3][qq][dd0+cc];
                ov[cc] = (__bf16)(o * rl);
            }
            *(bf16x4*)&AOb[(size_t)(b*SEQ + q0 + 32*i + qq) * DM
                           + h*HD + 32*dt + dd0] = ov;
            __syncthreads();   // comb reused next round
        }
    }
}

extern "C" void kernel_launch(void* const* d_in, const int* in_sizes, int n_in,
                              void* d_out, int out_size, void* d_ws, size_t ws_size,
                              hipStream_t stream) {
    const float* x  = (const float*)d_in[0];
    const float* Wq = (const float*)d_in[1];
    const float* Wk = (const float*)d_in[2];
    const float* Wv = (const float*)d_in[3];
    const float* Wo = (const float*)d_in[4];
    float* out = (float*)d_out;

    char* ws = (char*)d_ws;
    __bf16* xb    = (__bf16*)ws;                            // 8 MB [4096,1024]
    __bf16* Wqkvb = (__bf16*)(ws + ((size_t)8  << 20));     // 6 MB [3072,1024]
    __bf16* Wob   = (__bf16*)(ws + ((size_t)14 << 20));     // 2 MB [1024,1024]
    __bf16* Qb    = (__bf16*)(ws + ((size_t)16 << 20));     // 8 MB [b,h,s,d]
    __bf16* Kb    = (__bf16*)(ws + ((size_t)24 << 20));     // 8 MB [b,h,s,d]
    __bf16* Vtb   = (__bf16*)(ws + ((size_t)32 << 20));     // 8 MB [b,h,d,s]
    __bf16* AOb   = (__bf16*)(ws + ((size_t)40 << 20));     // 8 MB [4096,1024]

    cast_all<<<4096, 256, 0, stream>>>(x, Wq, Wk, Wv, Wo, xb, Wqkvb, Wob);

    // fused QKV projection + RoPE: M=4096, N=3072, 128x128 tile (m97 structure)
    gemm_mfma<128,128,0><<<dim3(MTOT/128, 3072/128), 256, 0, stream>>>(
        xb, Wqkvb, nullptr, Qb, Kb, Vtb);

    // causal MFMA flash attention -> bf16 AO; balanced 1024-block grid
    attn_mfma<<<dim3(BATCH*NHEADS, SEQ/128, 2), 256, 0, stream>>>(
        Qb, Kb, Vtb, AOb);

    // output projection: M=4096, N=1024, fp32 out, 128x128 tile
    gemm_mfma<128,128,1><<<dim3(MTOT/128, DM/128), 256, 0, stream>>>(
        AOb, Wob, out, nullptr, nullptr, nullptr);
}

// Round 9
// 174.380 us; speedup vs baseline: 1.0327x; 1.0327x over previous
//
#include <hip/hip_runtime.h>
#include <math.h>

#define NHEADS 16
#define HD 64
#define SEQ 2048
#define BATCH 2
#define DM 1024
#define MTOT (BATCH*SEQ)   // 4096
#define QT 128             // attn q-tile rows per block

typedef __bf16 bf16x8 __attribute__((ext_vector_type(8)));
typedef __bf16 bf16x4 __attribute__((ext_vector_type(4)));
typedef __bf16 bf16x2 __attribute__((ext_vector_type(2)));
typedef float  f32x4  __attribute__((ext_vector_type(4)));
typedef float  f32x16 __attribute__((ext_vector_type(16)));
typedef unsigned u32x2 __attribute__((ext_vector_type(2)));
typedef unsigned u32x4 __attribute__((ext_vector_type(4)));

#define LOG2E 1.4426950408889634f

// async global->LDS, 16B per lane; LDS side is wave-uniform base + lane*16
#define GLD16(gp, lp) __builtin_amdgcn_global_load_lds( \
    (const __attribute__((address_space(1))) void*)(gp), \
    (__attribute__((address_space(3))) void*)(lp), 16, 0, 0)

// ---------------- cast: x -> bf16, [Wq;Wk;Wv] -> Wqkv bf16, Wo -> bf16 ----
__global__ __launch_bounds__(256)
void cast_all(const float* __restrict__ x, const float* __restrict__ Wq,
              const float* __restrict__ Wk, const float* __restrict__ Wv,
              const float* __restrict__ Wo,
              __bf16* __restrict__ xb, __bf16* __restrict__ Wqkvb,
              __bf16* __restrict__ Wob)
{
    const size_t NX = (size_t)MTOT * DM;   // 4M
    const size_t NW_ = (size_t)DM * DM;    // 1M
    const size_t i = ((size_t)blockIdx.x * 256 + threadIdx.x) * 8;
    const float* src; __bf16* dst; size_t off;
    if (i < NX)               { src = x;  dst = xb;            off = i; }
    else if (i < NX + NW_)    { src = Wq; dst = Wqkvb;         off = i - NX; }
    else if (i < NX + 2*NW_)  { src = Wk; dst = Wqkvb + NW_;   off = i - NX - NW_; }
    else if (i < NX + 3*NW_)  { src = Wv; dst = Wqkvb + 2*NW_; off = i - NX - 2*NW_; }
    else                      { src = Wo; dst = Wob;           off = i - NX - 3*NW_; }
    const float4 f0 = *(const float4*)&src[off];
    const float4 f1 = *(const float4*)&src[off + 4];
    bf16x8 o;
    o[0] = (__bf16)f0.x; o[1] = (__bf16)f0.y; o[2] = (__bf16)f0.z; o[3] = (__bf16)f0.w;
    o[4] = (__bf16)f1.x; o[5] = (__bf16)f1.y; o[6] = (__bf16)f1.z; o[7] = (__bf16)f1.w;
    *(bf16x8*)&dst[off] = o;
}

// ---------------- MFMA GEMM: C[m,n] = sum_k A[m,k]*W[n,k], K=1024 ---------
// BM x BN tile, BK=64, 4 waves in 2x2 (wave-tile BM/2 x BN/2).
// LDS granules (16B) XOR-swizzled: global granule g of row r at slot g^(r&7)
// -> fragment ds_read_b128 spreads over all 8 bank groups (2-way = free).
// (256,3): ~168-reg cap fits 128x128 acc[4][4]; 3 blocks/CU.
// MODE 0: QKV epilogue with FUSED RoPE (Q scaled by 0.125*log2e, base-2
// softmax domain); Q/K -> [b,h,s,d] bf16, V -> [b,h,d,s] bf16.
// MODE 1: plain fp32 C.
template<int BM, int BN, int MODE>
__global__ __launch_bounds__(256, 3)
void gemm_mfma(const __bf16* __restrict__ A, const __bf16* __restrict__ W,
               float* __restrict__ Cf,
               __bf16* __restrict__ Qb, __bf16* __restrict__ Kb,
               __bf16* __restrict__ Vtb)
{
    constexpr int IT = BM / 32;        // i-tiles per wave
    constexpr int JT = BN / 32;        // j-tiles per wave
    __shared__ __bf16 As[BM * 64];
    __shared__ __bf16 Bs[BN * 64];

    const int tid  = threadIdx.x;
    const int lane = tid & 63;
    const int wave = tid >> 6;
    const int ll   = lane & 15;
    const int quad = lane >> 4;
    const int wm   = (wave & 1) * (BM / 2);
    const int wn   = (wave >> 1) * (BN / 2);
    const int bm   = blockIdx.x * BM;
    const int bn   = blockIdx.y * BN;

    const __bf16* Ab = A + (size_t)bm * DM;
    const __bf16* Wb = W + (size_t)bn * DM;

    f32x4 acc[IT][JT];
#pragma unroll
    for (int i = 0; i < IT; i++)
#pragma unroll
        for (int j = 0; j < JT; j++) acc[i][j] = (f32x4){0.f, 0.f, 0.f, 0.f};

    for (int k0 = 0; k0 < DM; k0 += 64) {
#pragma unroll
        for (int j = 0; j < BM / 32; j++) {
            const int t = tid + 256 * j;
            const int r = t >> 3, g = t & 7;
            GLD16(Ab + (size_t)r * DM + k0 + ((g ^ (r & 7)) * 8), &As[t * 8]);
        }
#pragma unroll
        for (int j = 0; j < BN / 32; j++) {
            const int t = tid + 256 * j;
            const int r = t >> 3, g = t & 7;
            GLD16(Wb + (size_t)r * DM + k0 + ((g ^ (r & 7)) * 8), &Bs[t * 8]);
        }
        __syncthreads();   // drains vmcnt -> LDS tiles valid

#pragma unroll
        for (int kh = 0; kh < 2; kh++) {
            bf16x8 af[IT], bfr[JT];
#pragma unroll
            for (int i = 0; i < IT; i++) {
                const int r = wm + i*16 + ll;
                const int g = kh*4 + quad;
                af[i] = *(const bf16x8*)&As[(r*8 + (g ^ (r & 7))) * 8];
            }
#pragma unroll
            for (int j = 0; j < JT; j++) {
                const int r = wn + j*16 + ll;
                const int g = kh*4 + quad;
                bfr[j] = *(const bf16x8*)&Bs[(r*8 + (g ^ (r & 7))) * 8];
            }
#pragma unroll
            for (int i = 0; i < IT; i++)
#pragma unroll
                for (int j = 0; j < JT; j++)
                    acc[i][j] = __builtin_amdgcn_mfma_f32_16x16x32_bf16(
                        af[i], bfr[j], acc[i][j], 0, 0, 0);
        }
        __syncthreads();
    }

    if (MODE == 1) {
#pragma unroll
        for (int i = 0; i < IT; i++) {
#pragma unroll
            for (int j = 0; j < JT; j++) {
                const int gc = bn + wn + j*16 + ll;
#pragma unroll
                for (int r = 0; r < 4; r++) {
                    const int gr = bm + wm + i*16 + quad*4 + r;
                    Cf[(size_t)gr * DM + gc] = acc[i][j][r];
                }
            }
        }
    } else {
        const int which = bn >> 10;    // 0=Q 1=K 2=V (BN-aligned within 1024)
        const int nb = bn & 1023;
#pragma unroll
        for (int i = 0; i < IT; i++) {
            const int m0 = bm + wm + i*16 + quad*4;
            const int b  = m0 >> 11;
            const int s0 = m0 & (SEQ - 1);
#pragma unroll
            for (int j = 0; j < JT; j++) {
                const int n_g = nb + wn + j*16 + ll;
                const int h = n_g >> 6, d = n_g & (HD - 1);
                if (which == 2) {
                    bf16x4 pk;
#pragma unroll
                    for (int r = 0; r < 4; r++) pk[r] = (__bf16)acc[i][j][r];
                    *(bf16x4*)&Vtb[((size_t)((b*NHEADS + h)*HD + d)) * SEQ + s0] = pk;
                } else {
                    // fused RoPE: pair (d even, d odd) sits in lanes (ll, ll^1)
                    __bf16* P = (which == 0) ? Qb : Kb;
                    const float sc = (which == 0) ? 0.125f * LOG2E : 1.0f;
                    const float inv =
                        exp2f(-(float)(d & ~1) * (13.287712379549449f / 64.0f));
                    const bool odd = (d & 1);
#pragma unroll
                    for (int r = 0; r < 4; r++) {
                        const float own = acc[i][j][r];
                        const float oth = __shfl_xor(own, 1);
                        float sn, cs;
                        __sincosf((float)(s0 + r) * inv, &sn, &cs);
                        const float xe = odd ? oth : own;
                        const float xo = odd ? own : oth;
                        const float o = odd ? (xe * sn + xo * cs)
                                            : (xe * cs - xo * sn);
                        P[((size_t)(b*NHEADS + h) * SEQ + s0 + r) * HD + d] =
                            (__bf16)(o * sc);
                    }
                }
            }
        }
    }
}

// pack 2 f32 -> 1 dword of 2 bf16 (elem0 = low bits)
static __device__ __forceinline__ unsigned pk2(float a, float b) {
    bf16x2 t; t[0] = (__bf16)a; t[1] = (__bf16)b;
    return __builtin_bit_cast(unsigned, t);
}

// ---------------- MFMA flash attention: LDS-staged K/V, in-register P -----
// R8: R7 proved attn is line-request-bound (more scattered V loads -> +31%
// dur; zero-LDS didn't help). Fix: block = 128 q-rows, wave w owns rows
// qw=128qb+32w x full d (complete O per wave -> NO cross-wave combine).
// Per 64-k unit, all 256 threads cooperatively stage K[64][64] and
// V^T[64][64] via GLD16 (coalesced: 128 lines/unit/BLOCK vs ~512/wave
// scattered), XOR-granule-swizzled exactly like the GEMM; fragments via
// conflict-free ds_read_b128/b64. Double-buffered: stage(t+1) issued before
// compute(t), barrier drain covered by compute. P stays in-register (R7's
// order-agnostic layout: A slots k={0..3,8..11}+4hi matched by permuted V
// reads). Balance: grid (32bh,8,2), qb=z?15-y:y -> each CU's 2 blocks sum
// to 36 units exactly.
// __launch_bounds__(256,2): cap 256 regs. NEVER cap at 128 (R9 spill note).
__global__ __launch_bounds__(256, 2)
void attn_mfma(const __bf16* __restrict__ Qb, const __bf16* __restrict__ Kb,
               const __bf16* __restrict__ Vtb, __bf16* __restrict__ AOb)
{
    __shared__ __align__(16) __bf16 Ks[2][64*64];  // 16 KB
    __shared__ __align__(16) __bf16 Vs[2][64*64];  // 16 KB
    __shared__ float lbuf[4][2][32];               // 1 KB

    const int tid  = threadIdx.x;
    const int wave = tid >> 6;
    const int lane = tid & 63;
    const int col  = lane & 31;
    const int hi   = lane >> 5;
    const int bh   = blockIdx.x;
    const int b    = bh >> 4, h = bh & 15;
    const int qb   = blockIdx.z ? (SEQ/QT - 1) - (int)blockIdx.y : (int)blockIdx.y;
    const int q0   = qb * QT;
    const int qw   = q0 + 32*wave;        // wave's q-block start (absolute)
    const int nk   = (q0 + QT) / 64;      // 64-k units to cover

    const __bf16* Qp = Qb + (size_t)bh * SEQ * HD;
    const __bf16* Kp = Kb + (size_t)bh * SEQ * HD;
    const __bf16* Vp = Vtb + (size_t)bh * HD * SEQ;

    // Q fragments (B-operand): qf[c] = Q[qw+col][16c+8hi .. +7]
    bf16x8 qf[4];
#pragma unroll
    for (int c = 0; c < 4; c++)
        qf[c] = *(const bf16x8*)&Qp[(size_t)(qw + col) * HD + 16*c + 8*hi];

    f32x16 acc[2];
    acc[0] = (f32x16){}; acc[1] = (f32x16){};
    float lsum = 0.f;
    const int cr = col - 4*hi;            // diag mask helper

    // prologue: stage unit 0 into buf 0
    {
#pragma unroll
        for (int j = 0; j < 2; j++) {
            const int ti = tid + 256*j, r = ti >> 3, g = ti & 7;
            GLD16(Kp + (size_t)r * HD + ((g ^ (r & 7)) * 8), &Ks[0][ti * 8]);
            GLD16(Vp + (size_t)r * SEQ + ((g ^ (r & 7)) * 8), &Vs[0][ti * 8]);
        }
    }
    __syncthreads();

    for (int t = 0; t < nk; t++) {
        // stage next unit into the other buffer (drained by end-of-loop sync)
        if (t + 1 < nk) {
            const int kn = (t + 1) * 64;
            const int bs = (t + 1) & 1;
#pragma unroll
            for (int j = 0; j < 2; j++) {
                const int ti = tid + 256*j, r = ti >> 3, g = ti & 7;
                GLD16(Kp + (size_t)(kn + r) * HD + ((g ^ (r & 7)) * 8),
                      &Ks[bs][ti * 8]);
                GLD16(Vp + (size_t)r * SEQ + kn + ((g ^ (r & 7)) * 8),
                      &Vs[bs][ti * 8]);
            }
        }

        const __bf16* Kt = Ks[t & 1];
        const __bf16* Vt = Vs[t & 1];

#pragma unroll
        for (int kt = 0; kt < 2; kt++) {
            const int kb = 64*t + 32*kt;          // subtile k start (absolute)
            if (kb > qw + 31) continue;           // wave-uniform: masked out

            const int R = 32*kt + col;
            bf16x8 kf[4];
#pragma unroll
            for (int c = 0; c < 4; c++)
                kf[c] = *(const bf16x8*)&Kt[(R*8 + ((2*c + hi) ^ (R & 7))) * 8];

            f32x16 s = (f32x16){};
#pragma unroll
            for (int c = 0; c < 4; c++)
                s = __builtin_amdgcn_mfma_f32_32x32x16_bf16(
                    kf[c], qf[c], s, 0, 0, 0);

            const bool tri = (kb == qw);
            float p[16];
#pragma unroll
            for (int r = 0; r < 16; r++) {
                float sv = s[r];
                if (tri && ((r & 3) + 8*(r >> 2) > cr)) sv = -INFINITY;
                p[r] = __builtin_amdgcn_exp2f(sv);
            }
            lsum += ((p[0]+p[1])+(p[2]+p[3])) + ((p[4]+p[5])+(p[6]+p[7]))
                  + ((p[8]+p[9])+(p[10]+p[11])) + ((p[12]+p[13])+(p[14]+p[15]));
            // natural per-lane pack (R7-verified): a0 slots = k {0..3,8..11}+4hi
            const u32x4 w0 = {pk2(p[0],  p[1]),  pk2(p[2],  p[3]),
                              pk2(p[4],  p[5]),  pk2(p[6],  p[7])};
            const u32x4 w1 = {pk2(p[8],  p[9]),  pk2(p[10], p[11]),
                              pk2(p[12], p[13]), pk2(p[14], p[15])};
            const bf16x8 a0 = __builtin_bit_cast(bf16x8, w0);
            const bf16x8 a1 = __builtin_bit_cast(bf16x8, w1);

#pragma unroll
            for (int dt = 0; dt < 2; dt++) {
                const int R2 = 32*dt + col;
                const int sw = R2 & 7;
                // permuted V rows matching a0/a1 slots (b64 pairs, swizzled)
                const u32x2 g0 = *(const u32x2*)&Vt[(R2*8 + ((4*kt + 0) ^ sw)) * 8 + 4*hi];
                const u32x2 g1 = *(const u32x2*)&Vt[(R2*8 + ((4*kt + 1) ^ sw)) * 8 + 4*hi];
                const u32x2 g2 = *(const u32x2*)&Vt[(R2*8 + ((4*kt + 2) ^ sw)) * 8 + 4*hi];
                const u32x2 g3 = *(const u32x2*)&Vt[(R2*8 + ((4*kt + 3) ^ sw)) * 8 + 4*hi];
                const u32x4 vv0 = {g0.x, g0.y, g1.x, g1.y};
                const u32x4 vv1 = {g2.x, g2.y, g3.x, g3.y};
                const bf16x8 v0 = __builtin_bit_cast(bf16x8, vv0);
                const bf16x8 v1 = __builtin_bit_cast(bf16x8, vv1);
                acc[dt] = __builtin_amdgcn_mfma_f32_32x32x16_bf16(
                    a0, v0, acc[dt], 0, 0, 0);
                acc[dt] = __builtin_amdgcn_mfma_f32_32x32x16_bf16(
                    a1, v1, acc[dt], 0, 0, 0);
            }
        }
        __syncthreads();   // buf[t^1] staged AND buf[t] fully consumed
    }

    // ---- epilogue: per-wave row sums, then direct O write ----
    lbuf[wave][hi][col] = lsum;
    __syncthreads();

#pragma unroll
    for (int dt = 0; dt < 2; dt++) {
#pragma unroll
        for (int r = 0; r < 16; r++) {
            const int row = (r & 3) + 8*(r >> 2) + 4*hi;
            const float rl = 1.0f / (lbuf[wave][0][row] + lbuf[wave][1][row]);
            AOb[(size_t)(b*SEQ + qw + row) * DM + h*HD + 32*dt + col] =
                (__bf16)(acc[dt][r] * rl);
        }
    }
}

extern "C" void kernel_launch(void* const* d_in, const int* in_sizes, int n_in,
                              void* d_out, int out_size, void* d_ws, size_t ws_size,
                              hipStream_t stream) {
    const float* x  = (const float*)d_in[0];
    const float* Wq = (const float*)d_in[1];
    const float* Wk = (const float*)d_in[2];
    const float* Wv = (const float*)d_in[3];
    const float* Wo = (const float*)d_in[4];
    float* out = (float*)d_out;

    char* ws = (char*)d_ws;
    __bf16* xb    = (__bf16*)ws;                            // 8 MB [4096,1024]
    __bf16* Wqkvb = (__bf16*)(ws + ((size_t)8  << 20));     // 6 MB [3072,1024]
    __bf16* Wob   = (__bf16*)(ws + ((size_t)14 << 20));     // 2 MB [1024,1024]
    __bf16* Qb    = (__bf16*)(ws + ((size_t)16 << 20));     // 8 MB [b,h,s,d]
    __bf16* Kb    = (__bf16*)(ws + ((size_t)24 << 20));     // 8 MB [b,h,s,d]
    __bf16* Vtb   = (__bf16*)(ws + ((size_t)32 << 20));     // 8 MB [b,h,d,s]
    __bf16* AOb   = (__bf16*)(ws + ((size_t)40 << 20));     // 8 MB [4096,1024]

    cast_all<<<4096, 256, 0, stream>>>(x, Wq, Wk, Wv, Wo, xb, Wqkvb, Wob);

    // fused QKV projection + RoPE: M=4096, N=3072, 128x128 tile (m97 structure)
    gemm_mfma<128,128,0><<<dim3(MTOT/128, 3072/128), 256, 0, stream>>>(
        xb, Wqkvb, nullptr, Qb, Kb, Vtb);

    // causal MFMA flash attention -> bf16 AO; 512 blocks, balanced pairs
    attn_mfma<<<dim3(BATCH*NHEADS, SEQ/QT/2, 2), 256, 0, stream>>>(
        Qb, Kb, Vtb, AOb);

    // output projection: M=4096, N=1024, fp32 out, 128x128 tile
    gemm_mfma<128,128,1><<<dim3(MTOT/128, DM/128), 256, 0, stream>>>(
        AOb, Wob, out, nullptr, nullptr, nullptr);
}

// Round 10
// 170.668 us; speedup vs baseline: 1.0551x; 1.0218x over previous
//
#include <hip/hip_runtime.h>
#include <math.h>

#define NHEADS 16
#define HD 64
#define SEQ 2048
#define BATCH 2
#define DM 1024
#define MTOT (BATCH*SEQ)   // 4096
#define QT 64              // attn q-tile rows per block (2 waves x 32)

typedef __bf16 bf16x8 __attribute__((ext_vector_type(8)));
typedef __bf16 bf16x4 __attribute__((ext_vector_type(4)));
typedef __bf16 bf16x2 __attribute__((ext_vector_type(2)));
typedef float  f32x4  __attribute__((ext_vector_type(4)));
typedef float  f32x16 __attribute__((ext_vector_type(16)));
typedef unsigned u32x2 __attribute__((ext_vector_type(2)));
typedef unsigned u32x4 __attribute__((ext_vector_type(4)));

#define LOG2E 1.4426950408889634f

// async global->LDS, 16B per lane; LDS side is wave-uniform base + lane*16
#define GLD16(gp, lp) __builtin_amdgcn_global_load_lds( \
    (const __attribute__((address_space(1))) void*)(gp), \
    (__attribute__((address_space(3))) void*)(lp), 16, 0, 0)

// ---------------- cast: x -> bf16, [Wq;Wk;Wv] -> Wqkv bf16, Wo -> bf16 ----
__global__ __launch_bounds__(256)
void cast_all(const float* __restrict__ x, const float* __restrict__ Wq,
              const float* __restrict__ Wk, const float* __restrict__ Wv,
              const float* __restrict__ Wo,
              __bf16* __restrict__ xb, __bf16* __restrict__ Wqkvb,
              __bf16* __restrict__ Wob)
{
    const size_t NX = (size_t)MTOT * DM;   // 4M
    const size_t NW_ = (size_t)DM * DM;    // 1M
    const size_t i = ((size_t)blockIdx.x * 256 + threadIdx.x) * 8;
    const float* src; __bf16* dst; size_t off;
    if (i < NX)               { src = x;  dst = xb;            off = i; }
    else if (i < NX + NW_)    { src = Wq; dst = Wqkvb;         off = i - NX; }
    else if (i < NX + 2*NW_)  { src = Wk; dst = Wqkvb + NW_;   off = i - NX - NW_; }
    else if (i < NX + 3*NW_)  { src = Wv; dst = Wqkvb + 2*NW_; off = i - NX - 2*NW_; }
    else                      { src = Wo; dst = Wob;           off = i - NX - 3*NW_; }
    const float4 f0 = *(const float4*)&src[off];
    const float4 f1 = *(const float4*)&src[off + 4];
    bf16x8 o;
    o[0] = (__bf16)f0.x; o[1] = (__bf16)f0.y; o[2] = (__bf16)f0.z; o[3] = (__bf16)f0.w;
    o[4] = (__bf16)f1.x; o[5] = (__bf16)f1.y; o[6] = (__bf16)f1.z; o[7] = (__bf16)f1.w;
    *(bf16x8*)&dst[off] = o;
}

// ---------------- MFMA GEMM: C[m,n] = sum_k A[m,k]*W[n,k], K=1024 ---------
// BM x BN tile, BK=64, 4 waves in 2x2 (wave-tile BM/2 x BN/2).
// LDS granules (16B) XOR-swizzled: global granule g of row r at slot g^(r&7)
// -> fragment ds_read_b128 spreads over all 8 bank groups (2-way = free).
// (256,3): ~168-reg cap fits 128x128 acc[4][4]; 3 blocks/CU.
// MODE 0: QKV epilogue with FUSED RoPE (Q scaled by 0.125*log2e, base-2
// softmax domain); Q/K -> [b,h,s,d] bf16, V -> [b,h,d,s] bf16.
// MODE 1: plain fp32 C.
template<int BM, int BN, int MODE>
__global__ __launch_bounds__(256, 3)
void gemm_mfma(const __bf16* __restrict__ A, const __bf16* __restrict__ W,
               float* __restrict__ Cf,
               __bf16* __restrict__ Qb, __bf16* __restrict__ Kb,
               __bf16* __restrict__ Vtb)
{
    constexpr int IT = BM / 32;        // i-tiles per wave
    constexpr int JT = BN / 32;        // j-tiles per wave
    __shared__ __bf16 As[BM * 64];
    __shared__ __bf16 Bs[BN * 64];

    const int tid  = threadIdx.x;
    const int lane = tid & 63;
    const int wave = tid >> 6;
    const int ll   = lane & 15;
    const int quad = lane >> 4;
    const int wm   = (wave & 1) * (BM / 2);
    const int wn   = (wave >> 1) * (BN / 2);
    const int bm   = blockIdx.x * BM;
    const int bn   = blockIdx.y * BN;

    const __bf16* Ab = A + (size_t)bm * DM;
    const __bf16* Wb = W + (size_t)bn * DM;

    f32x4 acc[IT][JT];
#pragma unroll
    for (int i = 0; i < IT; i++)
#pragma unroll
        for (int j = 0; j < JT; j++) acc[i][j] = (f32x4){0.f, 0.f, 0.f, 0.f};

    for (int k0 = 0; k0 < DM; k0 += 64) {
#pragma unroll
        for (int j = 0; j < BM / 32; j++) {
            const int t = tid + 256 * j;
            const int r = t >> 3, g = t & 7;
            GLD16(Ab + (size_t)r * DM + k0 + ((g ^ (r & 7)) * 8), &As[t * 8]);
        }
#pragma unroll
        for (int j = 0; j < BN / 32; j++) {
            const int t = tid + 256 * j;
            const int r = t >> 3, g = t & 7;
            GLD16(Wb + (size_t)r * DM + k0 + ((g ^ (r & 7)) * 8), &Bs[t * 8]);
        }
        __syncthreads();   // drains vmcnt -> LDS tiles valid

#pragma unroll
        for (int kh = 0; kh < 2; kh++) {
            bf16x8 af[IT], bfr[JT];
#pragma unroll
            for (int i = 0; i < IT; i++) {
                const int r = wm + i*16 + ll;
                const int g = kh*4 + quad;
                af[i] = *(const bf16x8*)&As[(r*8 + (g ^ (r & 7))) * 8];
            }
#pragma unroll
            for (int j = 0; j < JT; j++) {
                const int r = wn + j*16 + ll;
                const int g = kh*4 + quad;
                bfr[j] = *(const bf16x8*)&Bs[(r*8 + (g ^ (r & 7))) * 8];
            }
#pragma unroll
            for (int i = 0; i < IT; i++)
#pragma unroll
                for (int j = 0; j < JT; j++)
                    acc[i][j] = __builtin_amdgcn_mfma_f32_16x16x32_bf16(
                        af[i], bfr[j], acc[i][j], 0, 0, 0);
        }
        __syncthreads();
    }

    if (MODE == 1) {
#pragma unroll
        for (int i = 0; i < IT; i++) {
#pragma unroll
            for (int j = 0; j < JT; j++) {
                const int gc = bn + wn + j*16 + ll;
#pragma unroll
                for (int r = 0; r < 4; r++) {
                    const int gr = bm + wm + i*16 + quad*4 + r;
                    Cf[(size_t)gr * DM + gc] = acc[i][j][r];
                }
            }
        }
    } else {
        const int which = bn >> 10;    // 0=Q 1=K 2=V (BN-aligned within 1024)
        const int nb = bn & 1023;
#pragma unroll
        for (int i = 0; i < IT; i++) {
            const int m0 = bm + wm + i*16 + quad*4;
            const int b  = m0 >> 11;
            const int s0 = m0 & (SEQ - 1);
#pragma unroll
            for (int j = 0; j < JT; j++) {
                const int n_g = nb + wn + j*16 + ll;
                const int h = n_g >> 6, d = n_g & (HD - 1);
                if (which == 2) {
                    bf16x4 pk;
#pragma unroll
                    for (int r = 0; r < 4; r++) pk[r] = (__bf16)acc[i][j][r];
                    *(bf16x4*)&Vtb[((size_t)((b*NHEADS + h)*HD + d)) * SEQ + s0] = pk;
                } else {
                    // fused RoPE: pair (d even, d odd) sits in lanes (ll, ll^1)
                    __bf16* P = (which == 0) ? Qb : Kb;
                    const float sc = (which == 0) ? 0.125f * LOG2E : 1.0f;
                    const float inv =
                        exp2f(-(float)(d & ~1) * (13.287712379549449f / 64.0f));
                    const bool odd = (d & 1);
#pragma unroll
                    for (int r = 0; r < 4; r++) {
                        const float own = acc[i][j][r];
                        const float oth = __shfl_xor(own, 1);
                        float sn, cs;
                        __sincosf((float)(s0 + r) * inv, &sn, &cs);
                        const float xe = odd ? oth : own;
                        const float xo = odd ? own : oth;
                        const float o = odd ? (xe * sn + xo * cs)
                                            : (xe * cs - xo * sn);
                        P[((size_t)(b*NHEADS + h) * SEQ + s0 + r) * HD + d] =
                            (__bf16)(o * sc);
                    }
                }
            }
        }
    }
}

// pack 2 f32 -> 1 dword of 2 bf16 (elem0 = low bits)
static __device__ __forceinline__ unsigned pk2(float a, float b) {
    bf16x2 t; t[0] = (__bf16)a; t[1] = (__bf16)b;
    return __builtin_bit_cast(unsigned, t);
}

// ---------------- MFMA flash attention: LDS-staged K/V, in-register P -----
// R9: R8 was residency-starved (Occupancy 11.5%: QT=128 -> only 512 blocks
// at 33KB LDS = 2/CU, light blocks exit early -> heavy blocks alone at
// 1 wave/SIMD). Halve the tile: QT=64, 2-wave 128-thread blocks -> 1024
// blocks, 4 resident/CU = 16 waves/CU (2/SIMD). Per-wave fragment math is
// byte-identical to R8 (passed); total fragment reads conserved; staging
// doubles but is L2-resident (~80 B/cyc/CU << limits). Balance: qb=z?31-y:y
// -> each CU's 4 resident blocks sum to exactly 66 k-units. bh in
// blockIdx.x keeps each bh's K/V on one XCD L2 (flat%8 invariant in y,z).
// __launch_bounds__(128,2): cap 256 regs. NEVER cap at 128 (R9 spill note).
__global__ __launch_bounds__(128, 2)
void attn_mfma(const __bf16* __restrict__ Qb, const __bf16* __restrict__ Kb,
               const __bf16* __restrict__ Vtb, __bf16* __restrict__ AOb)
{
    __shared__ __align__(16) __bf16 Ks[2][64*64];  // 16 KB
    __shared__ __align__(16) __bf16 Vs[2][64*64];  // 16 KB
    __shared__ float lbuf[2][2][32];               // 0.5 KB

    const int tid  = threadIdx.x;
    const int wave = tid >> 6;            // 0..1
    const int lane = tid & 63;
    const int col  = lane & 31;
    const int hi   = lane >> 5;
    const int bh   = blockIdx.x;
    const int b    = bh >> 4, h = bh & 15;
    const int qb   = blockIdx.z ? (SEQ/QT - 1) - (int)blockIdx.y : (int)blockIdx.y;
    const int q0   = qb * QT;
    const int qw   = q0 + 32*wave;        // wave's q-block start (absolute)
    const int nk   = (q0 + QT) / 64;      // 64-k units to cover

    const __bf16* Qp = Qb + (size_t)bh * SEQ * HD;
    const __bf16* Kp = Kb + (size_t)bh * SEQ * HD;
    const __bf16* Vp = Vtb + (size_t)bh * HD * SEQ;

    // Q fragments (B-operand): qf[c] = Q[qw+col][16c+8hi .. +7]
    bf16x8 qf[4];
#pragma unroll
    for (int c = 0; c < 4; c++)
        qf[c] = *(const bf16x8*)&Qp[(size_t)(qw + col) * HD + 16*c + 8*hi];

    f32x16 acc[2];
    acc[0] = (f32x16){}; acc[1] = (f32x16){};
    float lsum = 0.f;
    const int cr = col - 4*hi;            // diag mask helper

    // prologue: stage unit 0 into buf 0 (128 threads x 4 iters per tensor)
    {
#pragma unroll
        for (int j = 0; j < 4; j++) {
            const int ti = tid + 128*j, r = ti >> 3, g = ti & 7;
            GLD16(Kp + (size_t)r * HD + ((g ^ (r & 7)) * 8), &Ks[0][ti * 8]);
            GLD16(Vp + (size_t)r * SEQ + ((g ^ (r & 7)) * 8), &Vs[0][ti * 8]);
        }
    }
    __syncthreads();

    for (int t = 0; t < nk; t++) {
        // stage next unit into the other buffer (drained by end-of-loop sync)
        if (t + 1 < nk) {
            const int kn = (t + 1) * 64;
            const int bs = (t + 1) & 1;
#pragma unroll
            for (int j = 0; j < 4; j++) {
                const int ti = tid + 128*j, r = ti >> 3, g = ti & 7;
                GLD16(Kp + (size_t)(kn + r) * HD + ((g ^ (r & 7)) * 8),
                      &Ks[bs][ti * 8]);
                GLD16(Vp + (size_t)r * SEQ + kn + ((g ^ (r & 7)) * 8),
                      &Vs[bs][ti * 8]);
            }
        }

        const __bf16* Kt = Ks[t & 1];
        const __bf16* Vt = Vs[t & 1];

#pragma unroll
        for (int kt = 0; kt < 2; kt++) {
            const int kb = 64*t + 32*kt;          // subtile k start (absolute)
            if (kb > qw + 31) continue;           // wave-uniform: masked out

            const int R = 32*kt + col;
            bf16x8 kf[4];
#pragma unroll
            for (int c = 0; c < 4; c++)
                kf[c] = *(const bf16x8*)&Kt[(R*8 + ((2*c + hi) ^ (R & 7))) * 8];

            f32x16 s = (f32x16){};
#pragma unroll
            for (int c = 0; c < 4; c++)
                s = __builtin_amdgcn_mfma_f32_32x32x16_bf16(
                    kf[c], qf[c], s, 0, 0, 0);

            const bool tri = (kb == qw);
            float p[16];
#pragma unroll
            for (int r = 0; r < 16; r++) {
                float sv = s[r];
                if (tri && ((r & 3) + 8*(r >> 2) > cr)) sv = -INFINITY;
                p[r] = __builtin_amdgcn_exp2f(sv);
            }
            lsum += ((p[0]+p[1])+(p[2]+p[3])) + ((p[4]+p[5])+(p[6]+p[7]))
                  + ((p[8]+p[9])+(p[10]+p[11])) + ((p[12]+p[13])+(p[14]+p[15]));
            // natural per-lane pack (R7-verified): a0 slots = k {0..3,8..11}+4hi
            const u32x4 w0 = {pk2(p[0],  p[1]),  pk2(p[2],  p[3]),
                              pk2(p[4],  p[5]),  pk2(p[6],  p[7])};
            const u32x4 w1 = {pk2(p[8],  p[9]),  pk2(p[10], p[11]),
                              pk2(p[12], p[13]), pk2(p[14], p[15])};
            const bf16x8 a0 = __builtin_bit_cast(bf16x8, w0);
            const bf16x8 a1 = __builtin_bit_cast(bf16x8, w1);

#pragma unroll
            for (int dt = 0; dt < 2; dt++) {
                const int R2 = 32*dt + col;
                const int sw = R2 & 7;
                // permuted V rows matching a0/a1 slots (b64 pairs, swizzled)
                const u32x2 g0 = *(const u32x2*)&Vt[(R2*8 + ((4*kt + 0) ^ sw)) * 8 + 4*hi];
                const u32x2 g1 = *(const u32x2*)&Vt[(R2*8 + ((4*kt + 1) ^ sw)) * 8 + 4*hi];
                const u32x2 g2 = *(const u32x2*)&Vt[(R2*8 + ((4*kt + 2) ^ sw)) * 8 + 4*hi];
                const u32x2 g3 = *(const u32x2*)&Vt[(R2*8 + ((4*kt + 3) ^ sw)) * 8 + 4*hi];
                const u32x4 vv0 = {g0.x, g0.y, g1.x, g1.y};
                const u32x4 vv1 = {g2.x, g2.y, g3.x, g3.y};
                const bf16x8 v0 = __builtin_bit_cast(bf16x8, vv0);
                const bf16x8 v1 = __builtin_bit_cast(bf16x8, vv1);
                acc[dt] = __builtin_amdgcn_mfma_f32_32x32x16_bf16(
                    a0, v0, acc[dt], 0, 0, 0);
                acc[dt] = __builtin_amdgcn_mfma_f32_32x32x16_bf16(
                    a1, v1, acc[dt], 0, 0, 0);
            }
        }
        __syncthreads();   // buf[t^1] staged AND buf[t] fully consumed
    }

    // ---- epilogue: per-wave row sums, then direct O write ----
    lbuf[wave][hi][col] = lsum;
    __syncthreads();

#pragma unroll
    for (int dt = 0; dt < 2; dt++) {
#pragma unroll
        for (int r = 0; r < 16; r++) {
            const int row = (r & 3) + 8*(r >> 2) + 4*hi;
            const float rl = 1.0f / (lbuf[wave][0][row] + lbuf[wave][1][row]);
            AOb[(size_t)(b*SEQ + qw + row) * DM + h*HD + 32*dt + col] =
                (__bf16)(acc[dt][r] * rl);
        }
    }
}

extern "C" void kernel_launch(void* const* d_in, const int* in_sizes, int n_in,
                              void* d_out, int out_size, void* d_ws, size_t ws_size,
                              hipStream_t stream) {
    const float* x  = (const float*)d_in[0];
    const float* Wq = (const float*)d_in[1];
    const float* Wk = (const float*)d_in[2];
    const float* Wv = (const float*)d_in[3];
    const float* Wo = (const float*)d_in[4];
    float* out = (float*)d_out;

    char* ws = (char*)d_ws;
    __bf16* xb    = (__bf16*)ws;                            // 8 MB [4096,1024]
    __bf16* Wqkvb = (__bf16*)(ws + ((size_t)8  << 20));     // 6 MB [3072,1024]
    __bf16* Wob   = (__bf16*)(ws + ((size_t)14 << 20));     // 2 MB [1024,1024]
    __bf16* Qb    = (__bf16*)(ws + ((size_t)16 << 20));     // 8 MB [b,h,s,d]
    __bf16* Kb    = (__bf16*)(ws + ((size_t)24 << 20));     // 8 MB [b,h,s,d]
    __bf16* Vtb   = (__bf16*)(ws + ((size_t)32 << 20));     // 8 MB [b,h,d,s]
    __bf16* AOb   = (__bf16*)(ws + ((size_t)40 << 20));     // 8 MB [4096,1024]

    cast_all<<<4096, 256, 0, stream>>>(x, Wq, Wk, Wv, Wo, xb, Wqkvb, Wob);

    // fused QKV projection + RoPE: M=4096, N=3072, 128x128 tile (m97 structure)
    gemm_mfma<128,128,0><<<dim3(MTOT/128, 3072/128), 256, 0, stream>>>(
        xb, Wqkvb, nullptr, Qb, Kb, Vtb);

    // causal MFMA flash attention -> bf16 AO; 1024 blocks, 4/CU, balanced
    attn_mfma<<<dim3(BATCH*NHEADS, SEQ/QT/2, 2), 128, 0, stream>>>(
        Qb, Kb, Vtb, AOb);

    // output projection: M=4096, N=1024, fp32 out, 128x128 tile
    gemm_mfma<128,128,1><<<dim3(MTOT/128, DM/128), 256, 0, stream>>>(
        AOb, Wob, out, nullptr, nullptr, nullptr);
}